// Round 10
// baseline (200.372 us; speedup 1.0000x reference)
//
#include <hip/hip_runtime.h>
#include <hip/hip_bf16.h>

#define NFEAT 9
#define VOCAB 119
#define HIDDEN 128
#define NHEAD 8
#define HDIM 16
#define KNBR 16

typedef __attribute__((ext_vector_type(8))) short short8;   // 8 bf16 = 4 VGPRs
typedef __attribute__((ext_vector_type(4))) float f32x4;    // MFMA C/D

// ---------- async global->LDS, 16B per lane (dest = wave-uniform base + lane*16) ----------
__device__ __forceinline__ void load_lds16(const void* g, void* l) {
    __builtin_amdgcn_global_load_lds((const __attribute__((address_space(1))) void*)g,
                                     (__attribute__((address_space(3))) void*)l, 16, 0, 0);
}

// ---------- sentinel fill (distinguishable failure signatures) ----------
__global__ void fill_kernel(float* out, int n, float val) {
    int i = blockIdx.x * blockDim.x + threadIdx.x;
    if (i < n) out[i] = val;
}

// ---------- Kernel 0: W -> W^T bf16 (one-time per launch, 12 blocks) ----------
__global__ __launch_bounds__(256) void wt_kernel(
    const float* __restrict__ Wq, const float* __restrict__ Wk,
    const float* __restrict__ Wv, short* __restrict__ Wt)
{
    int mat = blockIdx.x >> 2, tile = blockIdx.x & 3;  // 3 mats x 4 row-tiles
    const float* W = (mat == 0) ? Wq : (mat == 1) ? Wk : Wv;
    __shared__ float ls[32 * HIDDEN];
    int tid = threadIdx.x;
    int cc0 = tile * 32;
    #pragma unroll
    for (int j = 0; j < 16; ++j) {
        int idx = j * 256 + tid;
        ls[idx] = W[(size_t)cc0 * HIDDEN + idx];   // coalesced
    }
    __syncthreads();
    int c = tid & 127, hf = tid >> 7;  // thread: output row c, 16 cc's
    unsigned int ob[8];
    #pragma unroll
    for (int j = 0; j < 8; ++j) {
        int ccl = hf * 16 + 2 * j;
        __hip_bfloat16 b0 = __float2bfloat16(ls[ccl * HIDDEN + c]);
        __hip_bfloat16 b1 = __float2bfloat16(ls[(ccl + 1) * HIDDEN + c]);
        ob[j] = (unsigned int)*reinterpret_cast<unsigned short*>(&b0)
              | ((unsigned int)*reinterpret_cast<unsigned short*>(&b1) << 16);
    }
    unsigned int* dst = reinterpret_cast<unsigned int*>(
        Wt + (size_t)mat * HIDDEN * HIDDEN + (size_t)c * HIDDEN + cc0 + hf * 16);
    #pragma unroll
    for (int j = 0; j < 8; ++j) dst[j] = ob[j];
}

// ---------- Kernel 1: fused encoder + MFMA QKV ----------
// 64 nodes/block, 256 threads (4 waves). r9 post-mortem: Wb LDS staging
// (34.8KB) capped occupancy at 2 blocks/CU (16%) -> all pipes idle. Fix:
// B-fragments read DIRECTLY from global Wt (96KB, L2-resident; 16 distinct
// 64B lines per b128-load instruction). LDS now hb+xs = 19.7KB -> 6 blocks/CU,
// and only ONE barrier per block. A-fragments hoisted once (were re-read 3x).
#define MT 64
#define HBS 136  // padded bf16 row stride; 2-way LDS aliasing = free (m136)

__global__ __launch_bounds__(256) void qkv_kernel(
    const int* __restrict__ X, const float* __restrict__ emb,
    const short* __restrict__ Wt,
    const float* __restrict__ bq, const float* __restrict__ bk,
    const float* __restrict__ bv,
    float* __restrict__ qf, __hip_bfloat16* __restrict__ kv, int N)
{
    __shared__ __align__(16) short hb[MT * HBS];
    __shared__ int xs[MT * NFEAT];

    const int tid = threadIdx.x;
    const int n0 = blockIdx.x * MT;

    for (int i = tid; i < MT * NFEAT; i += 256) {
        int n = n0 + i / NFEAT;
        int v = (n < N) ? X[(size_t)n * NFEAT + (i % NFEAT)] : 0;
        xs[i] = min(max(v, 0), VOCAB - 1);  // clamp: never fault
    }
    __syncthreads();

    // ---- encoder: thread = (cg = float4 channel group, slot of 8 nodes) ----
    {
        const int cg = tid & 31;        // 32 groups x 4 channels
        const int slot = tid >> 5;      // 8 slots x 8 nodes
        #pragma unroll
        for (int i = 0; i < 8; ++i) {
            int nl = slot * 8 + i;
            float4 acc = {0.f, 0.f, 0.f, 0.f};
            #pragma unroll
            for (int f = 0; f < NFEAT; ++f) {
                const float4 e = *reinterpret_cast<const float4*>(
                    &emb[((size_t)f * VOCAB + xs[nl * NFEAT + f]) * HIDDEN + cg * 4]);
                acc.x += e.x; acc.y += e.y; acc.z += e.z; acc.w += e.w;
            }
            __hip_bfloat162 p0 = __float22bfloat162_rn(make_float2(acc.x, acc.y));
            __hip_bfloat162 p1 = __float22bfloat162_rn(make_float2(acc.z, acc.w));
            uint2 u;
            u.x = *reinterpret_cast<unsigned int*>(&p0);
            u.y = *reinterpret_cast<unsigned int*>(&p1);
            *reinterpret_cast<uint2*>(&hb[nl * HBS + cg * 4]) = u;  // 8B aligned
        }
    }
    __syncthreads();  // the only barrier: hb ready

    const int wave = tid >> 6, lane = tid & 63;
    const int l15 = lane & 15, quad = lane >> 4;
    const int mloc = wave * 16 + l15;  // A-operand row (node within tile)

    short8 a[4];
    #pragma unroll
    for (int k0 = 0; k0 < 4; ++k0)  // A[m=mloc][k=k0*32+quad*8 ..+7], hoisted
        a[k0] = *reinterpret_cast<const short8*>(&hb[mloc * HBS + k0 * 32 + quad * 8]);

    #pragma unroll
    for (int mat = 0; mat < 3; ++mat) {
        const short* Wm = Wt + (size_t)mat * HIDDEN * HIDDEN;
        const float* bias = (mat == 0) ? bq : (mat == 1) ? bk : bv;
        #pragma unroll
        for (int nt = 0; nt < 8; ++nt) {
            f32x4 acc = {0.f, 0.f, 0.f, 0.f};
            int n = nt * 16 + l15;         // output channel
            #pragma unroll
            for (int k0 = 0; k0 < 4; ++k0) {
                // global b128 load, L2-hit: 16 distinct 64B lines / instruction
                short8 b = *reinterpret_cast<const short8*>(
                    &Wm[n * HIDDEN + k0 * 32 + quad * 8]);
                acc = __builtin_amdgcn_mfma_f32_16x16x32_bf16(a[k0], b, acc, 0, 0, 0);
            }
            float bb = bias[n];
            #pragma unroll
            for (int r = 0; r < 4; ++r) {  // C row = quad*4+r = node within tile
                int node = n0 + wave * 16 + quad * 4 + r;
                if (node < N) {
                    float val = acc[r] + bb;
                    if (mat == 0)      qf[(size_t)node * HIDDEN + n] = val * 0.25f;
                    else if (mat == 1) kv[(size_t)node * 256 + n] = __float2bfloat16(val);
                    else               kv[(size_t)node * 256 + 128 + n] = __float2bfloat16(val);
                }
            }
        }
    }
}

// ---------------- Kernel 2: ELL sparse attention (frozen from r9) ----------------
#define NPB2 2

__global__ __launch_bounds__(256) void attn_kernel(
    const int* __restrict__ nbr_idx, const int* __restrict__ nbr_mask,
    const float* __restrict__ qf, const __hip_bfloat16* __restrict__ kv,
    float* __restrict__ out, int N)
{
    __shared__ __align__(16) __hip_bfloat16 kvl[NPB2][KNBR][256];
    __shared__ float ql[NPB2][HIDDEN];
    __shared__ float sl[NPB2][KNBR][NHEAD + 1];
    __shared__ float el[NPB2][KNBR][NHEAD + 1];
    __shared__ int idxl[NPB2][KNBR];
    __shared__ int mskl[NPB2][KNBR];

    const int tid = threadIdx.x;
    const int local = tid >> 7; // node within block
    const int t = tid & 127;    // thread within node
    int n = blockIdx.x * NPB2 + local;
    if (n >= N) n = N - 1;  // duplicate work, barrier-safe

    ql[local][t] = qf[(size_t)n * HIDDEN + t];
    if (t < KNBR) {
        int iv = nbr_idx[(size_t)n * KNBR + t];
        idxl[local][t] = min(max(iv, 0), N - 1);
        mskl[local][t] = nbr_mask[(size_t)n * KNBR + t];
    }
    __syncthreads();

    // gather: 4 global_load_lds(16B) per wave; wave covers 8 rows (2 per issue)
    {
        const int w2 = t >> 6;       // wave within node group (uniform per wave)
        const int l = t & 63;
        #pragma unroll
        for (int j = 0; j < 4; ++j) {
            int r = 4 * j + 2 * w2 + (l >> 5);   // row this lane feeds
            const short* src = (const short*)kv
                + (size_t)idxl[local][r] * 256 + (size_t)(l & 31) * 8;
            load_lds16(src, &kvl[local][4 * j + 2 * w2][0]);  // + lane*16 implicit
        }
    }
    __syncthreads();

    // scores: thread -> (nbr kk, head hh)
    const int kk = t >> 3, hh = t & 7;
    float s = 0.f;
    {
        const __hip_bfloat162* kp =
            reinterpret_cast<const __hip_bfloat162*>(&kvl[local][kk][hh * HDIM]);
        const float* qp = &ql[local][hh * HDIM];
        #pragma unroll
        for (int d2 = 0; d2 < HDIM / 2; ++d2) {
            float2 kf = __bfloat1622float2(kp[d2]);
            s += qp[2 * d2] * kf.x + qp[2 * d2 + 1] * kf.y;
        }
    }
    if (!mskl[local][kk]) s = -1e9f;
    sl[local][kk][hh] = s;
    __syncthreads();

    float mx = -3.0e38f;
    #pragma unroll
    for (int j = 0; j < KNBR; ++j) mx = fmaxf(mx, sl[local][j][hh]);
    float e = __expf(s - mx);
    el[local][kk][hh] = e;
    __syncthreads();
    float denom = 0.f;
    #pragma unroll
    for (int j = 0; j < KNBR; ++j) denom += el[local][j][hh];
    sl[local][kk][hh] = e / denom;  // reuse sl as attn weights
    __syncthreads();

    // PV: thread -> (head h2, dim dd)
    const int h2 = t >> 4, dd = t & 15;
    float o = 0.f;
    #pragma unroll
    for (int j = 0; j < KNBR; ++j) {
        float a = sl[local][j][h2];
        float vv = __bfloat162float(kvl[local][j][HIDDEN + h2 * HDIM + dd]);
        o += a * vv;
    }
    out[(size_t)n * HIDDEN + t] = o;  // OUTPUT IS FLOAT32 (verified r6)
}

extern "C" void kernel_launch(void* const* d_in, const int* in_sizes, int n_in,
                              void* d_out, int out_size, void* d_ws, size_t ws_size,
                              hipStream_t stream)
{
    float* out = (float*)d_out;

    bool ok = (n_in == 10);
    int N = ok ? in_sizes[0] / NFEAT : 0;
    ok = ok && N > 0 && in_sizes[0] == N * NFEAT
            && in_sizes[1] == N * KNBR
            && in_sizes[2] == N * KNBR
            && in_sizes[3] == NFEAT * VOCAB * HIDDEN
            && in_sizes[4] == HIDDEN * HIDDEN && in_sizes[5] == HIDDEN
            && in_sizes[6] == HIDDEN * HIDDEN && in_sizes[7] == HIDDEN
            && in_sizes[8] == HIDDEN * HIDDEN && in_sizes[9] == HIDDEN
            && out_size == N * HIDDEN;
    if (!ok) {
        fill_kernel<<<(out_size + 255) / 256, 256, 0, stream>>>(out, out_size, 0.0f);
        return;
    }
    size_t need = (size_t)N * 1024 + 3 * HIDDEN * HIDDEN * sizeof(short);
    if (ws_size < need) {
        fill_kernel<<<(out_size + 255) / 256, 256, 0, stream>>>(out, out_size, 1.0f);
        return;
    }

    const int* X        = (const int*)d_in[0];
    const int* nbr_idx  = (const int*)d_in[1];
    const int* nbr_mask = (const int*)d_in[2];
    const float* emb = (const float*)d_in[3];
    const float* Wq  = (const float*)d_in[4];
    const float* bq  = (const float*)d_in[5];
    const float* Wk  = (const float*)d_in[6];
    const float* bk  = (const float*)d_in[7];
    const float* Wv  = (const float*)d_in[8];
    const float* bv  = (const float*)d_in[9];

    // workspace: qf fp32 [N][128] | kv bf16 [N][256] | Wt bf16 [3][128][128]
    float* qf = (float*)d_ws;
    __hip_bfloat16* kv =
        (__hip_bfloat16*)((char*)d_ws + (size_t)N * HIDDEN * sizeof(float));
    short* Wt = (short*)((char*)d_ws + (size_t)N * 1024);

    wt_kernel<<<12, 256, 0, stream>>>(Wq, Wk, Wv, Wt);
    qkv_kernel<<<(N + MT - 1) / MT, 256, 0, stream>>>(
        X, emb, Wt, bq, bk, bv, qf, kv, N);
    attn_kernel<<<(N + NPB2 - 1) / NPB2, 256, 0, stream>>>(
        nbr_idx, nbr_mask, qf, kv, out, N);
}

// Round 11
// 196.090 us; speedup vs baseline: 1.0218x; 1.0218x over previous
//
#include <hip/hip_runtime.h>
#include <hip/hip_bf16.h>

#define NFEAT 9
#define VOCAB 119
#define HIDDEN 128
#define NHEAD 8
#define HDIM 16
#define KNBR 16

typedef __attribute__((ext_vector_type(8))) short short8;   // 8 bf16 = 4 VGPRs
typedef __attribute__((ext_vector_type(4))) float f32x4;    // MFMA C/D

// ---------- async global->LDS, 16B per lane (dest = wave-uniform base + lane*16) ----------
__device__ __forceinline__ void load_lds16(const void* g, void* l) {
    __builtin_amdgcn_global_load_lds((const __attribute__((address_space(1))) void*)g,
                                     (__attribute__((address_space(3))) void*)l, 16, 0, 0);
}

// ---------- sentinel fill (distinguishable failure signatures) ----------
__global__ void fill_kernel(float* out, int n, float val) {
    int i = blockIdx.x * blockDim.x + threadIdx.x;
    if (i < n) out[i] = val;
}

// ---------- Kernel 0: W -> W^T bf16 (one-time per launch, 12 blocks) ----------
__global__ __launch_bounds__(256) void wt_kernel(
    const float* __restrict__ Wq, const float* __restrict__ Wk,
    const float* __restrict__ Wv, short* __restrict__ Wt)
{
    int mat = blockIdx.x >> 2, tile = blockIdx.x & 3;  // 3 mats x 4 row-tiles
    const float* W = (mat == 0) ? Wq : (mat == 1) ? Wk : Wv;
    __shared__ float ls[32 * HIDDEN];
    int tid = threadIdx.x;
    int cc0 = tile * 32;
    #pragma unroll
    for (int j = 0; j < 16; ++j) {
        int idx = j * 256 + tid;
        ls[idx] = W[(size_t)cc0 * HIDDEN + idx];   // coalesced
    }
    __syncthreads();
    int c = tid & 127, hf = tid >> 7;  // thread: output row c, 16 cc's
    unsigned int ob[8];
    #pragma unroll
    for (int j = 0; j < 8; ++j) {
        int ccl = hf * 16 + 2 * j;
        __hip_bfloat16 b0 = __float2bfloat16(ls[ccl * HIDDEN + c]);
        __hip_bfloat16 b1 = __float2bfloat16(ls[(ccl + 1) * HIDDEN + c]);
        ob[j] = (unsigned int)*reinterpret_cast<unsigned short*>(&b0)
              | ((unsigned int)*reinterpret_cast<unsigned short*>(&b1) << 16);
    }
    unsigned int* dst = reinterpret_cast<unsigned int*>(
        Wt + (size_t)mat * HIDDEN * HIDDEN + (size_t)c * HIDDEN + cc0 + hf * 16);
    #pragma unroll
    for (int j = 0; j < 8; ++j) dst[j] = ob[j];
}

// ---------- Kernel 1: fused encoder + MFMA QKV ----------
// r10 post-mortem: 63.5us latency-bound — grid 782 blocks = 3/CU (occupancy 23%)
// AND VGPR_Count 40 = no load pipelining; all pipes <10%. This round:
//  (1) MT 64->32: grid 1563 = 6.1 blocks/CU;
//  (2) __launch_bounds__(256,4): VGPR cap 128 -> deep B-load pipeline;
//  (3) nt-outer loop: 12 independent B-loads (3 mats x 4 k0) issued as a burst
//      before their 12 MFMAs, 4-way nt unroll for cross-group pipelining.
#define MT 32
#define HBS 136  // padded bf16 row stride; 2-way LDS aliasing = free (m136)

__global__ __launch_bounds__(256, 4) void qkv_kernel(
    const int* __restrict__ X, const float* __restrict__ emb,
    const short* __restrict__ Wt,
    const float* __restrict__ bq, const float* __restrict__ bk,
    const float* __restrict__ bv,
    float* __restrict__ qf, __hip_bfloat16* __restrict__ kv, int N)
{
    __shared__ __align__(16) short hb[MT * HBS];
    __shared__ int xs[MT * NFEAT];

    const int tid = threadIdx.x;
    const int n0 = blockIdx.x * MT;

    for (int i = tid; i < MT * NFEAT; i += 256) {
        int n = n0 + i / NFEAT;
        int v = (n < N) ? X[(size_t)n * NFEAT + (i % NFEAT)] : 0;
        xs[i] = min(max(v, 0), VOCAB - 1);  // clamp: never fault
    }
    __syncthreads();

    // ---- encoder: thread = (cg = float4 channel group, slot of 4 nodes) ----
    {
        const int cg = tid & 31;        // 32 groups x 4 channels
        const int slot = tid >> 5;      // 8 slots x 4 nodes
        #pragma unroll
        for (int i = 0; i < 4; ++i) {
            int nl = slot * 4 + i;
            float4 acc = {0.f, 0.f, 0.f, 0.f};
            #pragma unroll
            for (int f = 0; f < NFEAT; ++f) {
                const float4 e = *reinterpret_cast<const float4*>(
                    &emb[((size_t)f * VOCAB + xs[nl * NFEAT + f]) * HIDDEN + cg * 4]);
                acc.x += e.x; acc.y += e.y; acc.z += e.z; acc.w += e.w;
            }
            __hip_bfloat162 p0 = __float22bfloat162_rn(make_float2(acc.x, acc.y));
            __hip_bfloat162 p1 = __float22bfloat162_rn(make_float2(acc.z, acc.w));
            uint2 u;
            u.x = *reinterpret_cast<unsigned int*>(&p0);
            u.y = *reinterpret_cast<unsigned int*>(&p1);
            *reinterpret_cast<uint2*>(&hb[nl * HBS + cg * 4]) = u;  // 8B aligned
        }
    }
    __syncthreads();  // the only barrier: hb ready

    // wave -> (m-tile of 16 nodes, half of the nt range)
    const int wave = tid >> 6, lane = tid & 63;
    const int l15 = lane & 15, quad = lane >> 4;
    const int mtile = wave & 1, nthalf = wave >> 1;
    const int mloc = mtile * 16 + l15;  // A-operand row (node within block)

    short8 a[4];
    #pragma unroll
    for (int k0 = 0; k0 < 4; ++k0)  // A[m=mloc][k=k0*32+quad*8 ..+7], hoisted
        a[k0] = *reinterpret_cast<const short8*>(&hb[mloc * HBS + k0 * 32 + quad * 8]);

    #pragma unroll
    for (int nt = 0; nt < 4; ++nt) {
        const int ntg = nthalf * 4 + nt;
        const int n = ntg * 16 + l15;      // output channel
        // burst: 12 independent b128 L2-hit loads (16 distinct 64B lines each)
        short8 b[3][4];
        #pragma unroll
        for (int mat = 0; mat < 3; ++mat)
            #pragma unroll
            for (int k0 = 0; k0 < 4; ++k0)
                b[mat][k0] = *reinterpret_cast<const short8*>(
                    &Wt[(size_t)mat * HIDDEN * HIDDEN + n * HIDDEN + k0 * 32 + quad * 8]);
        f32x4 acc[3] = {{0.f,0.f,0.f,0.f},{0.f,0.f,0.f,0.f},{0.f,0.f,0.f,0.f}};
        #pragma unroll
        for (int mat = 0; mat < 3; ++mat)
            #pragma unroll
            for (int k0 = 0; k0 < 4; ++k0)
                acc[mat] = __builtin_amdgcn_mfma_f32_16x16x32_bf16(
                    a[k0], b[mat][k0], acc[mat], 0, 0, 0);
        float bb[3] = {bq[n], bk[n], bv[n]};
        #pragma unroll
        for (int mat = 0; mat < 3; ++mat) {
            #pragma unroll
            for (int r = 0; r < 4; ++r) {  // C row = quad*4+r = node within m-tile
                int node = n0 + mtile * 16 + quad * 4 + r;
                if (node < N) {
                    float val = acc[mat][r] + bb[mat];
                    if (mat == 0)      qf[(size_t)node * HIDDEN + n] = val * 0.25f;
                    else if (mat == 1) kv[(size_t)node * 256 + n] = __float2bfloat16(val);
                    else               kv[(size_t)node * 256 + 128 + n] = __float2bfloat16(val);
                }
            }
        }
    }
}

// ---------------- Kernel 2: ELL sparse attention (frozen from r9) ----------------
#define NPB2 2

__global__ __launch_bounds__(256) void attn_kernel(
    const int* __restrict__ nbr_idx, const int* __restrict__ nbr_mask,
    const float* __restrict__ qf, const __hip_bfloat16* __restrict__ kv,
    float* __restrict__ out, int N)
{
    __shared__ __align__(16) __hip_bfloat16 kvl[NPB2][KNBR][256];
    __shared__ float ql[NPB2][HIDDEN];
    __shared__ float sl[NPB2][KNBR][NHEAD + 1];
    __shared__ float el[NPB2][KNBR][NHEAD + 1];
    __shared__ int idxl[NPB2][KNBR];
    __shared__ int mskl[NPB2][KNBR];

    const int tid = threadIdx.x;
    const int local = tid >> 7; // node within block
    const int t = tid & 127;    // thread within node
    int n = blockIdx.x * NPB2 + local;
    if (n >= N) n = N - 1;  // duplicate work, barrier-safe

    ql[local][t] = qf[(size_t)n * HIDDEN + t];
    if (t < KNBR) {
        int iv = nbr_idx[(size_t)n * KNBR + t];
        idxl[local][t] = min(max(iv, 0), N - 1);
        mskl[local][t] = nbr_mask[(size_t)n * KNBR + t];
    }
    __syncthreads();

    // gather: 4 global_load_lds(16B) per wave; wave covers 8 rows (2 per issue)
    {
        const int w2 = t >> 6;       // wave within node group (uniform per wave)
        const int l = t & 63;
        #pragma unroll
        for (int j = 0; j < 4; ++j) {
            int r = 4 * j + 2 * w2 + (l >> 5);   // row this lane feeds
            const short* src = (const short*)kv
                + (size_t)idxl[local][r] * 256 + (size_t)(l & 31) * 8;
            load_lds16(src, &kvl[local][4 * j + 2 * w2][0]);  // + lane*16 implicit
        }
    }
    __syncthreads();

    // scores: thread -> (nbr kk, head hh)
    const int kk = t >> 3, hh = t & 7;
    float s = 0.f;
    {
        const __hip_bfloat162* kp =
            reinterpret_cast<const __hip_bfloat162*>(&kvl[local][kk][hh * HDIM]);
        const float* qp = &ql[local][hh * HDIM];
        #pragma unroll
        for (int d2 = 0; d2 < HDIM / 2; ++d2) {
            float2 kf = __bfloat1622float2(kp[d2]);
            s += qp[2 * d2] * kf.x + qp[2 * d2 + 1] * kf.y;
        }
    }
    if (!mskl[local][kk]) s = -1e9f;
    sl[local][kk][hh] = s;
    __syncthreads();

    float mx = -3.0e38f;
    #pragma unroll
    for (int j = 0; j < KNBR; ++j) mx = fmaxf(mx, sl[local][j][hh]);
    float e = __expf(s - mx);
    el[local][kk][hh] = e;
    __syncthreads();
    float denom = 0.f;
    #pragma unroll
    for (int j = 0; j < KNBR; ++j) denom += el[local][j][hh];
    sl[local][kk][hh] = e / denom;  // reuse sl as attn weights
    __syncthreads();

    // PV: thread -> (head h2, dim dd)
    const int h2 = t >> 4, dd = t & 15;
    float o = 0.f;
    #pragma unroll
    for (int j = 0; j < KNBR; ++j) {
        float a = sl[local][j][h2];
        float vv = __bfloat162float(kvl[local][j][HIDDEN + h2 * HDIM + dd]);
        o += a * vv;
    }
    out[(size_t)n * HIDDEN + t] = o;  // OUTPUT IS FLOAT32 (verified r6)
}

extern "C" void kernel_launch(void* const* d_in, const int* in_sizes, int n_in,
                              void* d_out, int out_size, void* d_ws, size_t ws_size,
                              hipStream_t stream)
{
    float* out = (float*)d_out;

    bool ok = (n_in == 10);
    int N = ok ? in_sizes[0] / NFEAT : 0;
    ok = ok && N > 0 && in_sizes[0] == N * NFEAT
            && in_sizes[1] == N * KNBR
            && in_sizes[2] == N * KNBR
            && in_sizes[3] == NFEAT * VOCAB * HIDDEN
            && in_sizes[4] == HIDDEN * HIDDEN && in_sizes[5] == HIDDEN
            && in_sizes[6] == HIDDEN * HIDDEN && in_sizes[7] == HIDDEN
            && in_sizes[8] == HIDDEN * HIDDEN && in_sizes[9] == HIDDEN
            && out_size == N * HIDDEN;
    if (!ok) {
        fill_kernel<<<(out_size + 255) / 256, 256, 0, stream>>>(out, out_size, 0.0f);
        return;
    }
    size_t need = (size_t)N * 1024 + 3 * HIDDEN * HIDDEN * sizeof(short);
    if (ws_size < need) {
        fill_kernel<<<(out_size + 255) / 256, 256, 0, stream>>>(out, out_size, 1.0f);
        return;
    }

    const int* X        = (const int*)d_in[0];
    const int* nbr_idx  = (const int*)d_in[1];
    const int* nbr_mask = (const int*)d_in[2];
    const float* emb = (const float*)d_in[3];
    const float* Wq  = (const float*)d_in[4];
    const float* bq  = (const float*)d_in[5];
    const float* Wk  = (const float*)d_in[6];
    const float* bk  = (const float*)d_in[7];
    const float* Wv  = (const float*)d_in[8];
    const float* bv  = (const float*)d_in[9];

    // workspace: qf fp32 [N][128] | kv bf16 [N][256] | Wt bf16 [3][128][128]
    float* qf = (float*)d_ws;
    __hip_bfloat16* kv =
        (__hip_bfloat16*)((char*)d_ws + (size_t)N * HIDDEN * sizeof(float));
    short* Wt = (short*)((char*)d_ws + (size_t)N * 1024);

    wt_kernel<<<12, 256, 0, stream>>>(Wq, Wk, Wv, Wt);
    qkv_kernel<<<(N + MT - 1) / MT, 256, 0, stream>>>(
        X, emb, Wt, bq, bk, bv, qf, kv, N);
    attn_kernel<<<(N + NPB2 - 1) / NPB2, 256, 0, stream>>>(
        nbr_idx, nbr_mask, qf, kv, out, N);
}

// Round 12
// 186.572 us; speedup vs baseline: 1.0740x; 1.0510x over previous
//
#include <hip/hip_runtime.h>
#include <hip/hip_bf16.h>

#define NFEAT 9
#define VOCAB 119
#define HIDDEN 128
#define NHEAD 8
#define HDIM 16
#define KNBR 16

typedef __attribute__((ext_vector_type(8))) short short8;   // 8 bf16 = 4 VGPRs
typedef __attribute__((ext_vector_type(4))) float f32x4;    // MFMA C/D

// ---------- async global->LDS, 16B per lane (dest = wave-uniform base + lane*16) ----------
__device__ __forceinline__ void load_lds16(const void* g, void* l) {
    __builtin_amdgcn_global_load_lds((const __attribute__((address_space(1))) void*)g,
                                     (__attribute__((address_space(3))) void*)l, 16, 0, 0);
}

// ---------- sentinel fill (distinguishable failure signatures) ----------
__global__ void fill_kernel(float* out, int n, float val) {
    int i = blockIdx.x * blockDim.x + threadIdx.x;
    if (i < n) out[i] = val;
}

// ---------- Kernel 0: W -> W^T bf16 (one-time per launch, 12 blocks) ----------
__global__ __launch_bounds__(256) void wt_kernel(
    const float* __restrict__ Wq, const float* __restrict__ Wk,
    const float* __restrict__ Wv, short* __restrict__ Wt)
{
    int mat = blockIdx.x >> 2, tile = blockIdx.x & 3;  // 3 mats x 4 row-tiles
    const float* W = (mat == 0) ? Wq : (mat == 1) ? Wk : Wv;
    __shared__ float ls[32 * HIDDEN];
    int tid = threadIdx.x;
    int cc0 = tile * 32;
    #pragma unroll
    for (int j = 0; j < 16; ++j) {
        int idx = j * 256 + tid;
        ls[idx] = W[(size_t)cc0 * HIDDEN + idx];   // coalesced
    }
    __syncthreads();
    int c = tid & 127, hf = tid >> 7;  // thread: output row c, 16 cc's
    unsigned int ob[8];
    #pragma unroll
    for (int j = 0; j < 8; ++j) {
        int ccl = hf * 16 + 2 * j;
        __hip_bfloat16 b0 = __float2bfloat16(ls[ccl * HIDDEN + c]);
        __hip_bfloat16 b1 = __float2bfloat16(ls[(ccl + 1) * HIDDEN + c]);
        ob[j] = (unsigned int)*reinterpret_cast<unsigned short*>(&b0)
              | ((unsigned int)*reinterpret_cast<unsigned short*>(&b1) << 16);
    }
    unsigned int* dst = reinterpret_cast<unsigned int*>(
        Wt + (size_t)mat * HIDDEN * HIDDEN + (size_t)c * HIDDEN + cc0 + hf * 16);
    #pragma unroll
    for (int j = 0; j < 8; ++j) dst[j] = ob[j];
}

// ---------- Kernel 1: fused encoder + MFMA QKV (FROZEN from r11) ----------
#define MT 32
#define HBS 136  // padded bf16 row stride; 2-way LDS aliasing = free (m136)

__global__ __launch_bounds__(256, 4) void qkv_kernel(
    const int* __restrict__ X, const float* __restrict__ emb,
    const short* __restrict__ Wt,
    const float* __restrict__ bq, const float* __restrict__ bk,
    const float* __restrict__ bv,
    float* __restrict__ qf, __hip_bfloat16* __restrict__ kv, int N)
{
    __shared__ __align__(16) short hb[MT * HBS];
    __shared__ int xs[MT * NFEAT];

    const int tid = threadIdx.x;
    const int n0 = blockIdx.x * MT;

    for (int i = tid; i < MT * NFEAT; i += 256) {
        int n = n0 + i / NFEAT;
        int v = (n < N) ? X[(size_t)n * NFEAT + (i % NFEAT)] : 0;
        xs[i] = min(max(v, 0), VOCAB - 1);  // clamp: never fault
    }
    __syncthreads();

    // ---- encoder: thread = (cg = float4 channel group, slot of 4 nodes) ----
    {
        const int cg = tid & 31;        // 32 groups x 4 channels
        const int slot = tid >> 5;      // 8 slots x 4 nodes
        #pragma unroll
        for (int i = 0; i < 4; ++i) {
            int nl = slot * 4 + i;
            float4 acc = {0.f, 0.f, 0.f, 0.f};
            #pragma unroll
            for (int f = 0; f < NFEAT; ++f) {
                const float4 e = *reinterpret_cast<const float4*>(
                    &emb[((size_t)f * VOCAB + xs[nl * NFEAT + f]) * HIDDEN + cg * 4]);
                acc.x += e.x; acc.y += e.y; acc.z += e.z; acc.w += e.w;
            }
            __hip_bfloat162 p0 = __float22bfloat162_rn(make_float2(acc.x, acc.y));
            __hip_bfloat162 p1 = __float22bfloat162_rn(make_float2(acc.z, acc.w));
            uint2 u;
            u.x = *reinterpret_cast<unsigned int*>(&p0);
            u.y = *reinterpret_cast<unsigned int*>(&p1);
            *reinterpret_cast<uint2*>(&hb[nl * HBS + cg * 4]) = u;  // 8B aligned
        }
    }
    __syncthreads();  // the only barrier: hb ready

    const int wave = tid >> 6, lane = tid & 63;
    const int l15 = lane & 15, quad = lane >> 4;
    const int mtile = wave & 1, nthalf = wave >> 1;
    const int mloc = mtile * 16 + l15;  // A-operand row (node within block)

    short8 a[4];
    #pragma unroll
    for (int k0 = 0; k0 < 4; ++k0)  // A[m=mloc][k=k0*32+quad*8 ..+7], hoisted
        a[k0] = *reinterpret_cast<const short8*>(&hb[mloc * HBS + k0 * 32 + quad * 8]);

    #pragma unroll
    for (int nt = 0; nt < 4; ++nt) {
        const int ntg = nthalf * 4 + nt;
        const int n = ntg * 16 + l15;      // output channel
        short8 b[3][4];
        #pragma unroll
        for (int mat = 0; mat < 3; ++mat)
            #pragma unroll
            for (int k0 = 0; k0 < 4; ++k0)
                b[mat][k0] = *reinterpret_cast<const short8*>(
                    &Wt[(size_t)mat * HIDDEN * HIDDEN + n * HIDDEN + k0 * 32 + quad * 8]);
        f32x4 acc[3] = {{0.f,0.f,0.f,0.f},{0.f,0.f,0.f,0.f},{0.f,0.f,0.f,0.f}};
        #pragma unroll
        for (int mat = 0; mat < 3; ++mat)
            #pragma unroll
            for (int k0 = 0; k0 < 4; ++k0)
                acc[mat] = __builtin_amdgcn_mfma_f32_16x16x32_bf16(
                    a[k0], b[mat][k0], acc[mat], 0, 0, 0);
        float bb[3] = {bq[n], bk[n], bv[n]};
        #pragma unroll
        for (int mat = 0; mat < 3; ++mat) {
            #pragma unroll
            for (int r = 0; r < 4; ++r) {  // C row = quad*4+r = node within m-tile
                int node = n0 + mtile * 16 + quad * 4 + r;
                if (node < N) {
                    float val = acc[mat][r] + bb[mat];
                    if (mat == 0)      qf[(size_t)node * HIDDEN + n] = val * 0.25f;
                    else if (mat == 1) kv[(size_t)node * 256 + n] = __float2bfloat16(val);
                    else               kv[(size_t)node * 256 + 128 + n] = __float2bfloat16(val);
                }
            }
        }
    }
}

// ---------------- Kernel 2: ELL sparse attention (reworked r12) ----------------
// 2 nodes/block. Changes vs r11 (which had 8-way score-phase bank conflicts,
// 5 barriers, and fetched k-rows of masked-out neighbors):
//  - row-PAIR padding 16B (pair stride 260 words = 4-bank shift): score k-reads
//    as 2x ds_read_b128 with t=hh*16+kk map -> 8 start-bank groups = bandwidth-
//    minimal; PV v-reads stay 2-way broadcast (free).
//  - k-half gather lanes predicated on nbr_mask (~50% fewer k lines fetched);
//    v-half always loaded (exactness of rare all-masked uniform-average case).
//  - softmax inlined in PV (recompute max/exp/denom from raw scores): 3 barriers
//    total, el/ql arrays deleted; q loaded global->regs during gather window.
#define NPB2 2
#define PAIRW 520  // bf16 elems per row-pair slot: 2*256 + 8 pad (1040B, 260 words)

__global__ __launch_bounds__(256) void attn_kernel(
    const int* __restrict__ nbr_idx, const int* __restrict__ nbr_mask,
    const float* __restrict__ qf, const __hip_bfloat16* __restrict__ kv,
    float* __restrict__ out, int N)
{
    __shared__ __align__(16) __hip_bfloat16 kvp[NPB2][8][PAIRW];
    __shared__ float sl[NPB2][KNBR][NHEAD + 1];
    __shared__ int idxl[NPB2][KNBR];
    __shared__ int mskl[NPB2][KNBR];

    const int tid = threadIdx.x;
    const int local = tid >> 7; // node within block
    const int t = tid & 127;    // thread within node
    int n = blockIdx.x * NPB2 + local;
    if (n >= N) n = N - 1;  // duplicate work, barrier-safe

    if (t < KNBR) {
        int iv = nbr_idx[(size_t)n * KNBR + t];
        idxl[local][t] = min(max(iv, 0), N - 1);
        mskl[local][t] = nbr_mask[(size_t)n * KNBR + t];
    }
    __syncthreads();

    const int hh = t >> 4;   // head (0..7), same for score & PV phases
    const int kk = t & 15;   // neighbor for score phase / dd for PV phase

    // q -> registers (address depends on head only: 8 x 64B lines per wave,
    // L2-hit; overlaps the kv gather below)
    float qr[HDIM];
    {
        const float4* qp = reinterpret_cast<const float4*>(
            qf + (size_t)n * HIDDEN + hh * HDIM);
        #pragma unroll
        for (int c4 = 0; c4 < 4; ++c4) {
            float4 qv = qp[c4];
            qr[4 * c4 + 0] = qv.x; qr[4 * c4 + 1] = qv.y;
            qr[4 * c4 + 2] = qv.z; qr[4 * c4 + 3] = qv.w;
        }
    }

    // gather: 4 pair-loads per wave; k-half lanes predicated on mask
    {
        const int w2 = t >> 6;       // uniform per wave
        const int l = t & 63;
        #pragma unroll
        for (int j = 0; j < 4; ++j) {
            int pair = 2 * j + w2;
            int r = pair * 2 + (l >> 5);          // neighbor row this lane feeds
            bool khalf = (l & 31) < 16;           // first 256B = k
            if (!khalf || mskl[local][r]) {
                const short* src = (const short*)kv
                    + (size_t)idxl[local][r] * 256 + (size_t)(l & 31) * 8;
                load_lds16(src, &kvp[local][pair][0]);  // + lane*16 implicit
            }
        }
    }
    __syncthreads();

    // scores: thread (hh, kk); k as 2x ds_read_b128
    {
        const short8* kb = reinterpret_cast<const short8*>(
            &kvp[local][kk >> 1][(kk & 1) * 256 + hh * HDIM]);
        short8 k0 = kb[0], k1 = kb[1];
        const __hip_bfloat162* kp0 = reinterpret_cast<const __hip_bfloat162*>(&k0);
        const __hip_bfloat162* kp1 = reinterpret_cast<const __hip_bfloat162*>(&k1);
        float s = 0.f;
        #pragma unroll
        for (int d2 = 0; d2 < 4; ++d2) {
            float2 f0 = __bfloat1622float2(kp0[d2]);
            float2 f1 = __bfloat1622float2(kp1[d2]);
            s += qr[2 * d2] * f0.x + qr[2 * d2 + 1] * f0.y;
            s += qr[8 + 2 * d2] * f1.x + qr[8 + 2 * d2 + 1] * f1.y;
        }
        if (!mskl[local][kk]) s = -1e9f;   // overwrite, NaN-safe
        sl[local][kk][hh] = s;
    }
    __syncthreads();

    // PV with inline softmax: thread (h2=hh, dd=kk); out channel = t
    {
        const int dd = kk;
        float sj[KNBR];
        #pragma unroll
        for (int j = 0; j < KNBR; ++j) sj[j] = sl[local][j][hh];
        float mx = sj[0];
        #pragma unroll
        for (int j = 1; j < KNBR; ++j) mx = fmaxf(mx, sj[j]);
        float e[KNBR], denom = 0.f;
        #pragma unroll
        for (int j = 0; j < KNBR; ++j) { e[j] = __expf(sj[j] - mx); denom += e[j]; }
        float inv = 1.f / denom;           // all-masked -> uniform 1/16 (exact)
        float o = 0.f;
        #pragma unroll
        for (int j = 0; j < KNBR; ++j) {
            float vv = __bfloat162float(
                kvp[local][j >> 1][(j & 1) * 256 + HIDDEN + hh * HDIM + dd]);
            o += e[j] * vv;
        }
        out[(size_t)n * HIDDEN + t] = o * inv;  // OUTPUT IS FLOAT32 (verified r6)
    }
}

extern "C" void kernel_launch(void* const* d_in, const int* in_sizes, int n_in,
                              void* d_out, int out_size, void* d_ws, size_t ws_size,
                              hipStream_t stream)
{
    float* out = (float*)d_out;

    bool ok = (n_in == 10);
    int N = ok ? in_sizes[0] / NFEAT : 0;
    ok = ok && N > 0 && in_sizes[0] == N * NFEAT
            && in_sizes[1] == N * KNBR
            && in_sizes[2] == N * KNBR
            && in_sizes[3] == NFEAT * VOCAB * HIDDEN
            && in_sizes[4] == HIDDEN * HIDDEN && in_sizes[5] == HIDDEN
            && in_sizes[6] == HIDDEN * HIDDEN && in_sizes[7] == HIDDEN
            && in_sizes[8] == HIDDEN * HIDDEN && in_sizes[9] == HIDDEN
            && out_size == N * HIDDEN;
    if (!ok) {
        fill_kernel<<<(out_size + 255) / 256, 256, 0, stream>>>(out, out_size, 0.0f);
        return;
    }
    size_t need = (size_t)N * 1024 + 3 * HIDDEN * HIDDEN * sizeof(short);
    if (ws_size < need) {
        fill_kernel<<<(out_size + 255) / 256, 256, 0, stream>>>(out, out_size, 1.0f);
        return;
    }

    const int* X        = (const int*)d_in[0];
    const int* nbr_idx  = (const int*)d_in[1];
    const int* nbr_mask = (const int*)d_in[2];
    const float* emb = (const float*)d_in[3];
    const float* Wq  = (const float*)d_in[4];
    const float* bq  = (const float*)d_in[5];
    const float* Wk  = (const float*)d_in[6];
    const float* bk  = (const float*)d_in[7];
    const float* Wv  = (const float*)d_in[8];
    const float* bv  = (const float*)d_in[9];

    // workspace: qf fp32 [N][128] | kv bf16 [N][256] | Wt bf16 [3][128][128]
    float* qf = (float*)d_ws;
    __hip_bfloat16* kv =
        (__hip_bfloat16*)((char*)d_ws + (size_t)N * HIDDEN * sizeof(float));
    short* Wt = (short*)((char*)d_ws + (size_t)N * 1024);

    wt_kernel<<<12, 256, 0, stream>>>(Wq, Wk, Wv, Wt);
    qkv_kernel<<<(N + MT - 1) / MT, 256, 0, stream>>>(
        X, emb, Wt, bq, bk, bv, qf, kv, N);
    attn_kernel<<<(N + NPB2 - 1) / NPB2, 256, 0, stream>>>(
        nbr_idx, nbr_mask, qf, kv, out, N);
}

// Round 14
// 168.201 us; speedup vs baseline: 1.1913x; 1.1092x over previous
//
#include <hip/hip_runtime.h>
#include <hip/hip_bf16.h>

#define NFEAT 9
#define VOCAB 119
#define HIDDEN 128
#define NHEAD 8
#define HDIM 16
#define KNBR 16

typedef __attribute__((ext_vector_type(8))) short short8;   // 8 bf16 = 4 VGPRs
typedef __attribute__((ext_vector_type(4))) float f32x4;    // MFMA C/D

// ---------- async global->LDS, 16B per lane (dest = wave-uniform base + lane*16) ----------
__device__ __forceinline__ void load_lds16(const void* g, void* l) {
    __builtin_amdgcn_global_load_lds((const __attribute__((address_space(1))) void*)g,
                                     (__attribute__((address_space(3))) void*)l, 16, 0, 0);
}

// ---------- sentinel fill (distinguishable failure signatures) ----------
__global__ void fill_kernel(float* out, int n, float val) {
    int i = blockIdx.x * blockDim.x + threadIdx.x;
    if (i < n) out[i] = val;
}

// ---------- Kernel 0: W -> W^T bf16 (one-time per launch, 12 blocks) ----------
__global__ __launch_bounds__(256) void wt_kernel(
    const float* __restrict__ Wq, const float* __restrict__ Wk,
    const float* __restrict__ Wv, short* __restrict__ Wt)
{
    int mat = blockIdx.x >> 2, tile = blockIdx.x & 3;  // 3 mats x 4 row-tiles
    const float* W = (mat == 0) ? Wq : (mat == 1) ? Wk : Wv;
    __shared__ float ls[32 * HIDDEN];
    int tid = threadIdx.x;
    int cc0 = tile * 32;
    #pragma unroll
    for (int j = 0; j < 16; ++j) {
        int idx = j * 256 + tid;
        ls[idx] = W[(size_t)cc0 * HIDDEN + idx];   // coalesced
    }
    __syncthreads();
    int c = tid & 127, hf = tid >> 7;  // thread: output row c, 16 cc's
    unsigned int ob[8];
    #pragma unroll
    for (int j = 0; j < 8; ++j) {
        int ccl = hf * 16 + 2 * j;
        __hip_bfloat16 b0 = __float2bfloat16(ls[ccl * HIDDEN + c]);
        __hip_bfloat16 b1 = __float2bfloat16(ls[(ccl + 1) * HIDDEN + c]);
        ob[j] = (unsigned int)*reinterpret_cast<unsigned short*>(&b0)
              | ((unsigned int)*reinterpret_cast<unsigned short*>(&b1) << 16);
    }
    unsigned int* dst = reinterpret_cast<unsigned int*>(
        Wt + (size_t)mat * HIDDEN * HIDDEN + (size_t)c * HIDDEN + cc0 + hf * 16);
    #pragma unroll
    for (int j = 0; j < 8; ++j) dst[j] = ob[j];
}

// ---------- Kernel 1: fused encoder + MFMA QKV (r12 dataflow, B-stationary) ----------
// r13 post-mortem: splitting encoder to a separate kernel with a global hbg
// handoff passed validation but DIVERGED on graph replay (call-1-right,
// later-calls-wrong). Reverted to the r12-proven fused dataflow (only Wt
// handoff, replay-clean since r8). Kept r13's real improvement: B-stationary —
// each wave loads its 24 B-fragments (2 ch-groups x 3 mats x 4 k0 = 96 VGPRs)
// from global Wt ONCE and reuses across both m-tiles. Structural register
// pressure forces the deep load pipeline (r11/r12 compiler sat at VGPR 36-40).
#define MT 32
#define HBS 136  // padded bf16 row stride; 2-way LDS aliasing = free (m136)

__global__ __launch_bounds__(256, 3) void qkv_kernel(
    const int* __restrict__ X, const float* __restrict__ emb,
    const short* __restrict__ Wt,
    const float* __restrict__ bq, const float* __restrict__ bk,
    const float* __restrict__ bv,
    float* __restrict__ qf, __hip_bfloat16* __restrict__ kv, int N)
{
    __shared__ __align__(16) short hb[MT * HBS];
    __shared__ int xs[MT * NFEAT];

    const int tid = threadIdx.x;
    const int n0 = blockIdx.x * MT;

    for (int i = tid; i < MT * NFEAT; i += 256) {
        int n = n0 + i / NFEAT;
        int v = (n < N) ? X[(size_t)n * NFEAT + (i % NFEAT)] : 0;
        xs[i] = min(max(v, 0), VOCAB - 1);  // clamp: never fault
    }
    __syncthreads();

    // ---- encoder: thread = (cg = float4 channel group, slot of 4 nodes) ----
    // (exact r12 code — proven correct & replay-safe)
    {
        const int cg = tid & 31;        // 32 groups x 4 channels
        const int slot = tid >> 5;      // 8 slots x 4 nodes
        #pragma unroll
        for (int i = 0; i < 4; ++i) {
            int nl = slot * 4 + i;
            float4 acc = {0.f, 0.f, 0.f, 0.f};
            #pragma unroll
            for (int f = 0; f < NFEAT; ++f) {
                const float4 e = *reinterpret_cast<const float4*>(
                    &emb[((size_t)f * VOCAB + xs[nl * NFEAT + f]) * HIDDEN + cg * 4]);
                acc.x += e.x; acc.y += e.y; acc.z += e.z; acc.w += e.w;
            }
            __hip_bfloat162 p0 = __float22bfloat162_rn(make_float2(acc.x, acc.y));
            __hip_bfloat162 p1 = __float22bfloat162_rn(make_float2(acc.z, acc.w));
            uint2 u;
            u.x = *reinterpret_cast<unsigned int*>(&p0);
            u.y = *reinterpret_cast<unsigned int*>(&p1);
            *reinterpret_cast<uint2*>(&hb[nl * HBS + cg * 4]) = u;  // 8B aligned
        }
    }
    __syncthreads();  // hb ready

    const int wave = tid >> 6, lane = tid & 63;
    const int l15 = lane & 15, quad = lane >> 4;

    // B stationary: wave owns channel groups wave*2, wave*2+1 (once per block)
    short8 b[2][3][4];
    float bias[2][3];
    #pragma unroll
    for (int g = 0; g < 2; ++g) {
        const int n = (wave * 2 + g) * 16 + l15;   // output channel
        #pragma unroll
        for (int mat = 0; mat < 3; ++mat) {
            #pragma unroll
            for (int k0 = 0; k0 < 4; ++k0)
                b[g][mat][k0] = *reinterpret_cast<const short8*>(
                    &Wt[(size_t)mat * HIDDEN * HIDDEN + n * HIDDEN + k0 * 32 + quad * 8]);
            bias[g][mat] = (mat == 0) ? bq[n] : (mat == 1) ? bk[n] : bv[n];
        }
    }

    #pragma unroll
    for (int mt = 0; mt < 2; ++mt) {
        const int mloc = mt * 16 + l15;          // A row (node within block)
        short8 a[4];
        #pragma unroll
        for (int k0 = 0; k0 < 4; ++k0)           // A[m][k=k0*32+quad*8..+7]
            a[k0] = *reinterpret_cast<const short8*>(
                &hb[mloc * HBS + k0 * 32 + quad * 8]);
        #pragma unroll
        for (int g = 0; g < 2; ++g) {
            const int n = (wave * 2 + g) * 16 + l15;
            f32x4 acc[3] = {{0.f,0.f,0.f,0.f},{0.f,0.f,0.f,0.f},{0.f,0.f,0.f,0.f}};
            #pragma unroll
            for (int mat = 0; mat < 3; ++mat)
                #pragma unroll
                for (int k0 = 0; k0 < 4; ++k0)
                    acc[mat] = __builtin_amdgcn_mfma_f32_16x16x32_bf16(
                        a[k0], b[g][mat][k0], acc[mat], 0, 0, 0);
            #pragma unroll
            for (int mat = 0; mat < 3; ++mat) {
                #pragma unroll
                for (int r = 0; r < 4; ++r) {    // C row = quad*4+r (node in m-tile)
                    int node = n0 + mt * 16 + quad * 4 + r;
                    if (node < N) {
                        float val = acc[mat][r] + bias[g][mat];
                        if (mat == 0)      qf[(size_t)node * HIDDEN + n] = val * 0.25f;
                        else if (mat == 1) kv[(size_t)node * 256 + n] = __float2bfloat16(val);
                        else               kv[(size_t)node * 256 + 128 + n] = __float2bfloat16(val);
                    }
                }
            }
        }
    }
}

// ---------------- Kernel 2: ELL sparse attention (FROZEN from r12) ----------------
#define NPB2 2
#define PAIRW 520  // bf16 elems per row-pair slot: 2*256 + 8 pad (1040B, 260 words)

__global__ __launch_bounds__(256) void attn_kernel(
    const int* __restrict__ nbr_idx, const int* __restrict__ nbr_mask,
    const float* __restrict__ qf, const __hip_bfloat16* __restrict__ kv,
    float* __restrict__ out, int N)
{
    __shared__ __align__(16) __hip_bfloat16 kvp[NPB2][8][PAIRW];
    __shared__ float sl[NPB2][KNBR][NHEAD + 1];
    __shared__ int idxl[NPB2][KNBR];
    __shared__ int mskl[NPB2][KNBR];

    const int tid = threadIdx.x;
    const int local = tid >> 7; // node within block
    const int t = tid & 127;    // thread within node
    int n = blockIdx.x * NPB2 + local;
    if (n >= N) n = N - 1;  // duplicate work, barrier-safe

    if (t < KNBR) {
        int iv = nbr_idx[(size_t)n * KNBR + t];
        idxl[local][t] = min(max(iv, 0), N - 1);
        mskl[local][t] = nbr_mask[(size_t)n * KNBR + t];
    }
    __syncthreads();

    const int hh = t >> 4;   // head (0..7)
    const int kk = t & 15;   // neighbor (scores) / dd (PV)

    float qr[HDIM];
    {
        const float4* qp = reinterpret_cast<const float4*>(
            qf + (size_t)n * HIDDEN + hh * HDIM);
        #pragma unroll
        for (int c4 = 0; c4 < 4; ++c4) {
            float4 qv = qp[c4];
            qr[4 * c4 + 0] = qv.x; qr[4 * c4 + 1] = qv.y;
            qr[4 * c4 + 2] = qv.z; qr[4 * c4 + 3] = qv.w;
        }
    }

    // gather: 4 pair-loads per wave; k-half lanes predicated on mask
    {
        const int w2 = t >> 6;       // uniform per wave
        const int l = t & 63;
        #pragma unroll
        for (int j = 0; j < 4; ++j) {
            int pair = 2 * j + w2;
            int r = pair * 2 + (l >> 5);          // neighbor row this lane feeds
            bool khalf = (l & 31) < 16;           // first 256B = k
            if (!khalf || mskl[local][r]) {
                const short* src = (const short*)kv
                    + (size_t)idxl[local][r] * 256 + (size_t)(l & 31) * 8;
                load_lds16(src, &kvp[local][pair][0]);  // + lane*16 implicit
            }
        }
    }
    __syncthreads();

    // scores: thread (hh, kk); k as 2x ds_read_b128
    {
        const short8* kb = reinterpret_cast<const short8*>(
            &kvp[local][kk >> 1][(kk & 1) * 256 + hh * HDIM]);
        short8 k0 = kb[0], k1 = kb[1];
        const __hip_bfloat162* kp0 = reinterpret_cast<const __hip_bfloat162*>(&k0);
        const __hip_bfloat162* kp1 = reinterpret_cast<const __hip_bfloat162*>(&k1);
        float s = 0.f;
        #pragma unroll
        for (int d2 = 0; d2 < 4; ++d2) {
            float2 f0 = __bfloat1622float2(kp0[d2]);
            float2 f1 = __bfloat1622float2(kp1[d2]);
            s += qr[2 * d2] * f0.x + qr[2 * d2 + 1] * f0.y;
            s += qr[8 + 2 * d2] * f1.x + qr[8 + 2 * d2 + 1] * f1.y;
        }
        if (!mskl[local][kk]) s = -1e9f;
        sl[local][kk][hh] = s;
    }
    __syncthreads();

    // PV with inline softmax: thread (hh, dd=kk); out channel = t
    {
        const int dd = kk;
        float sj[KNBR];
        #pragma unroll
        for (int j = 0; j < KNBR; ++j) sj[j] = sl[local][j][hh];
        float mx = sj[0];
        #pragma unroll
        for (int j = 1; j < KNBR; ++j) mx = fmaxf(mx, sj[j]);
        float e[KNBR], denom = 0.f;
        #pragma unroll
        for (int j = 0; j < KNBR; ++j) { e[j] = __expf(sj[j] - mx); denom += e[j]; }
        float inv = 1.f / denom;           // all-masked -> uniform 1/16 (exact)
        float o = 0.f;
        #pragma unroll
        for (int j = 0; j < KNBR; ++j) {
            float vv = __bfloat162float(
                kvp[local][j >> 1][(j & 1) * 256 + HIDDEN + hh * HDIM + dd]);
            o += e[j] * vv;
        }
        out[(size_t)n * HIDDEN + t] = o * inv;  // OUTPUT IS FLOAT32 (verified r6)
    }
}

extern "C" void kernel_launch(void* const* d_in, const int* in_sizes, int n_in,
                              void* d_out, int out_size, void* d_ws, size_t ws_size,
                              hipStream_t stream)
{
    float* out = (float*)d_out;

    bool ok = (n_in == 10);
    int N = ok ? in_sizes[0] / NFEAT : 0;
    ok = ok && N > 0 && in_sizes[0] == N * NFEAT
            && in_sizes[1] == N * KNBR
            && in_sizes[2] == N * KNBR
            && in_sizes[3] == NFEAT * VOCAB * HIDDEN
            && in_sizes[4] == HIDDEN * HIDDEN && in_sizes[5] == HIDDEN
            && in_sizes[6] == HIDDEN * HIDDEN && in_sizes[7] == HIDDEN
            && in_sizes[8] == HIDDEN * HIDDEN && in_sizes[9] == HIDDEN
            && out_size == N * HIDDEN;
    if (!ok) {
        fill_kernel<<<(out_size + 255) / 256, 256, 0, stream>>>(out, out_size, 0.0f);
        return;
    }
    size_t need = (size_t)N * 1024 + 3 * HIDDEN * HIDDEN * sizeof(short);
    if (ws_size < need) {
        fill_kernel<<<(out_size + 255) / 256, 256, 0, stream>>>(out, out_size, 1.0f);
        return;
    }

    const int* X        = (const int*)d_in[0];
    const int* nbr_idx  = (const int*)d_in[1];
    const int* nbr_mask = (const int*)d_in[2];
    const float* emb = (const float*)d_in[3];
    const float* Wq  = (const float*)d_in[4];
    const float* bq  = (const float*)d_in[5];
    const float* Wk  = (const float*)d_in[6];
    const float* bk  = (const float*)d_in[7];
    const float* Wv  = (const float*)d_in[8];
    const float* bv  = (const float*)d_in[9];

    // workspace: qf fp32 [N][128] | kv bf16 [N][256] | Wt bf16 [3][128][128]
    float* qf = (float*)d_ws;
    __hip_bfloat16* kv =
        (__hip_bfloat16*)((char*)d_ws + (size_t)N * HIDDEN * sizeof(float));
    short* Wt = (short*)((char*)d_ws + (size_t)N * 1024);

    wt_kernel<<<12, 256, 0, stream>>>(Wq, Wk, Wv, Wt);
    qkv_kernel<<<(N + MT - 1) / MT, 256, 0, stream>>>(
        X, emb, Wt, bq, bk, bv, qf, kv, N);
    attn_kernel<<<(N + NPB2 - 1) / NPB2, 256, 0, stream>>>(
        nbr_idx, nbr_mask, qf, kv, out, N);
}